// Round 14
// baseline (347.899 us; speedup 1.0000x reference)
//
#include <hip/hip_runtime.h>

#define T_STEPS 512
#define INPUT   13
#define HIDDEN  64
#define MB      16    // full MFMA M-tile, grid 256 = 1 block/CU
#define CS      8     // timesteps per x-chunk
#define NCHUNK  (T_STEPS / CS)
#define NTHREADS 512  // 8 waves: gate-type = w>>1, col-tile pair = (w&1)*2
#define LOG2E   1.44269504088896f

typedef __attribute__((ext_vector_type(8))) _Float16 f16x8;  // MFMA A/B frag
typedef __attribute__((ext_vector_type(4)))  float   f32x4;  // MFMA C/D frag

__device__ __forceinline__ float exp2_f(float x) { return __builtin_amdgcn_exp2f(x); }
__device__ __forceinline__ float rcp_f(float x)  { return __builtin_amdgcn_rcpf(x); }
__device__ __forceinline__ float sigmoid_f(float x) {           // epilogue only
    return rcp_f(1.0f + exp2_f(-LOG2E * x));
}

// R13 post-mortem: concept (8-wave split, 2 waves/SIMD, zero duplicated work)
// sound; execution killed by (1) launch_bounds(512) w/o 2nd arg -> VGPR
// squeezed to 40 (every (N,1) build allocated naturally: 88-132), (2) gl
// [gt][row][col] 4-way bank conflicts (22M = 168 cyc/step/CU), (3) b32-
// granular exchange. R14 fixes: launch_bounds(512,1); gl transposed to
// [gt][col][row pad 20] -> D-frag = ONE b128 write (bank-groups (5lr+lg)%8
// = all 8, 2-way free), cell unit = (row-pair, cell) -> 4 b64 reads, c kept
// as reg pair; h-writes 2 b16 (2-way free). Exchange 18 -> 8 LDS ops/lane.
// Numerics byte-identical to R12/R13 -> absmax must be exactly 0.00390625.
__global__ __launch_bounds__(NTHREADS, 1)
void lstm_mfma_kernel(const float* __restrict__ x,
                      const float* __restrict__ W_ih,
                      const float* __restrict__ W_hh,
                      const float* __restrict__ b_ih,
                      const float* __restrict__ b_hh,
                      const float* __restrict__ W_fc,
                      const float* __restrict__ b_fc,
                      float* __restrict__ out)
{
    __shared__ _Float16 hA[2][MB][HIDDEN];     // 4 KB, XOR-swizzled (R12 layout)
    __shared__ _Float16 xA[2][CS][MB][32];     // 16 KB (R12 layout)
    __shared__ float    gl[4][HIDDEN][20];     // 20 KB exchange, col-major padded
    __shared__ float    hf[MB][HIDDEN];        // 4 KB epilogue

    const int tid = threadIdx.x;
    const int w   = tid >> 6;        // wave 0..7
    const int l   = tid & 63;
    const int lr  = l & 15;
    const int lg  = l >> 4;
    const int gt  = w >> 1;          // this wave's gate type (0=i,1=f,2=g,3=o)
    const int cgb = (w & 1) * 2;     // first of two owned col-tiles
    const int row0 = blockIdx.x * MB;

    // ---- resident weight B-frags: 2 tiles x {x, h0, h1} ----
    const float scl = (gt == 2) ? (2.0f * LOG2E) : (-LOG2E);
    f16x8 Bh[2][2], Bx[2];
    f32x4 biasv[2];
    #pragma unroll
    for (int t = 0; t < 2; ++t) {
        const int gate = gt * 64 + (cgb + t) * 16 + lr;
        const float b  = scl * (b_ih[gate] + b_hh[gate]);
        biasv[t] = (f32x4){b, b, b, b};
        #pragma unroll
        for (int kf = 0; kf < 2; ++kf)
            #pragma unroll
            for (int j = 0; j < 8; ++j)
                Bh[t][kf][j] = (_Float16)(scl * W_hh[gate * HIDDEN + kf * 32 + lg * 8 + j]);
        #pragma unroll
        for (int j = 0; j < 8; ++j) {
            const int k = lg * 8 + j;
            Bx[t][j] = (_Float16)((k < INPUT) ? scl * W_ih[gate * INPUT + k] : 0.0f);
        }
    }

    // ---- precomputed LDS pointers ----
    const f16x8* phr[2][2];          // h A-frag reads (R12 pattern)
    #pragma unroll
    for (int hb = 0; hb < 2; ++hb)
        #pragma unroll
        for (int kf = 0; kf < 2; ++kf) {
            const int slot = (kf * 4 + lg) ^ (lr & 7);
            phr[hb][kf] = (const f16x8*)((const char*)&hA[hb][lr][0] + slot * 16);
        }
    const int slx = lg ^ (lr & 3);   // x A-frag reads
    const f16x8* px = (const f16x8*)((const char*)&xA[0][0][lr][0] + slx * 16);

    // gl writes: tile t -> col (cgb+t)*16+lr, rows lg*4..lg*4+3 = one b128
    float* pglw[2];
    #pragma unroll
    for (int t = 0; t < 2; ++t)
        pglw[t] = &gl[gt][(cgb + t) * 16 + lr][lg * 4];

    // cell unit: (row-pair rp = w, cell = l) -> reads 4 x b64, gt stride 1280
    const float* pglr = &gl[0][l][2 * w];

    // h writes: rows 2w, 2w+1 at swizzled slots for cell l
    _Float16* pwh[2][2];             // [hb][u]
    #pragma unroll
    for (int hb = 0; hb < 2; ++hb)
        #pragma unroll
        for (int u = 0; u < 2; ++u) {
            const int row = 2 * w + u;
            const int kp  = (l & 7) | (((l >> 3) ^ (row & 7)) << 3);
            pwh[hb][u] = &hA[hb][row][kp];
        }

    // ---- zero LDS (h0 = 0; x pad slots stay 0 forever) ----
    for (int i = tid; i < 2 * MB * HIDDEN; i += NTHREADS)
        ((unsigned short*)hA)[i] = 0;
    for (int i = tid; i < 2 * CS * MB * 32; i += NTHREADS)
        ((unsigned short*)xA)[i] = 0;

    float c[2]    = {0.f, 0.f};
    float hreg[2] = {0.f, 0.f};

    // ---- x chunk loader: 2048 slots / 512 threads = 4 each ----
    float stg[4];
    auto load_chunk = [&](int ch) {
        #pragma unroll
        for (int s = 0; s < 4; ++s) {
            const int idx = tid + s * NTHREADS;  // 0..2047
            const int i   = idx & 15;
            const int tt  = (idx >> 4) & 7;
            const int r   = idx >> 7;            // 0..15
            float v = 0.0f;
            if (i < INPUT)
                v = x[(size_t)(row0 + r) * (T_STEPS * INPUT)
                      + (size_t)(ch * CS + tt) * INPUT + i];
            stg[s] = v;
        }
    };
    auto store_chunk = [&](int buf) {
        #pragma unroll
        for (int s = 0; s < 4; ++s) {
            const int idx = tid + s * NTHREADS;
            const int i   = idx & 15;
            const int tt  = (idx >> 4) & 7;
            const int r   = idx >> 7;
            const int kp  = (i & 7) | (((i >> 3) ^ (r & 3)) << 3);
            xA[buf][tt][r][kp] = (_Float16)stg[s];
        }
    };

    load_chunk(0);
    __syncthreads();          // zero-init visible
    store_chunk(0);
    __syncthreads();

    for (int ch = 0; ch < NCHUNK; ++ch) {
        const int cur = ch & 1;
        const f16x8* pxc = px + cur * 512;
        if (ch + 1 < NCHUNK)
            load_chunk(ch + 1);          // global loads in flight over 8 steps

        #pragma unroll
        for (int tt = 0; tt < CS; ++tt) {
            const int hb  = tt & 1;      // read parity (CS even -> consistent)
            const int hbw = hb ^ 1;      // write parity

            // ---- A-frag reads (shared by both tiles) ----
            const f16x8 ax  = pxc[tt * 64];
            const f16x8 ah0 = phr[hb][0][0];
            const f16x8 ah1 = phr[hb][1][0];

            // ---- 2 tiles x 3-deep MFMA chain (bias as C-in) ----
            f32x4 a0 = biasv[0], a1 = biasv[1];
            a0 = __builtin_amdgcn_mfma_f32_16x16x32_f16(ax,  Bx[0],    a0, 0, 0, 0);
            a1 = __builtin_amdgcn_mfma_f32_16x16x32_f16(ax,  Bx[1],    a1, 0, 0, 0);
            a0 = __builtin_amdgcn_mfma_f32_16x16x32_f16(ah0, Bh[0][0], a0, 0, 0, 0);
            a1 = __builtin_amdgcn_mfma_f32_16x16x32_f16(ah0, Bh[1][0], a1, 0, 0, 0);
            a0 = __builtin_amdgcn_mfma_f32_16x16x32_f16(ah1, Bh[0][1], a0, 0, 0, 0);
            a1 = __builtin_amdgcn_mfma_f32_16x16x32_f16(ah1, Bh[1][1], a1, 0, 0, 0);

            // ---- publish pre-activations: ONE b128 per tile ----
            *(f32x4*)pglw[0] = a0;
            *(f32x4*)pglw[1] = a1;
            __syncthreads();

            // ---- cell update: unit (row-pair, cell), 4 b64 reads ----
            const float2 vA = *(const float2*)(pglr + 0 * 1280);
            const float2 vF = *(const float2*)(pglr + 1 * 1280);
            const float2 vB = *(const float2*)(pglr + 2 * 1280);
            const float2 vO = *(const float2*)(pglr + 3 * 1280);
            #pragma unroll
            for (int u = 0; u < 2; ++u) {
                const float A = exp2_f(u ? vA.y : vA.x);
                const float F = exp2_f(u ? vF.y : vF.x);
                const float B = exp2_f(u ? vB.y : vB.x);
                const float O = exp2_f(u ? vO.y : vO.x);
                const float ig = (B - 1.0f) * rcp_f((1.0f + A) * (1.0f + B));
                const float cn = fmaf(c[u], rcp_f(1.0f + F), ig);
                c[u] = cn;
                const float T = exp2_f((2.0f * LOG2E) * cn);
                const float h = (T - 1.0f) * rcp_f((1.0f + O) * (1.0f + T));
                hreg[u] = h;
                pwh[hbw][u][0] = (_Float16)h;
            }

            // fold chunk staging into the last step (no extra barrier)
            if (tt == CS - 1 && ch + 1 < NCHUNK)
                store_chunk(1 - cur);

            __syncthreads();
        }
    }

    // ---- epilogue: out[row] = sigmoid(h_T . W_fc + b_fc) ----
    hf[2 * w][l]     = hreg[0];
    hf[2 * w + 1][l] = hreg[1];
    __syncthreads();
    if (tid < MB) {
        float a = b_fc[0];
        #pragma unroll
        for (int j = 0; j < HIDDEN; ++j)
            a = fmaf(hf[tid][j], W_fc[j], a);
        out[row0 + tid] = sigmoid_f(a);
    }
}

extern "C" void kernel_launch(void* const* d_in, const int* in_sizes, int n_in,
                              void* d_out, int out_size, void* d_ws, size_t ws_size,
                              hipStream_t stream) {
    const float* x    = (const float*)d_in[0];
    const float* W_ih = (const float*)d_in[1];
    const float* W_hh = (const float*)d_in[2];
    const float* b_ih = (const float*)d_in[3];
    const float* b_hh = (const float*)d_in[4];
    const float* W_fc = (const float*)d_in[5];
    const float* b_fc = (const float*)d_in[6];
    float* out = (float*)d_out;

    const int B = 4096;
    dim3 grid(B / MB), block(NTHREADS);
    lstm_mfma_kernel<<<grid, block, 0, stream>>>(x, W_ih, W_hh, b_ih, b_hh,
                                                 W_fc, b_fc, out);
}

// Round 15
// 333.308 us; speedup vs baseline: 1.0438x; 1.0438x over previous
//
#include <hip/hip_runtime.h>

#define T_STEPS 512
#define INPUT   13
#define HIDDEN  64
#define MB      16    // full MFMA M-tile, grid 256 = 1 block/CU
#define CS      8     // timesteps per x-chunk
#define NCHUNK  (T_STEPS / CS)
#define NTHREADS 1024 // 16 waves x 1 gate-tile: gt = v>>2, cell-group = v&3
#define GLS     28    // gl row stride (floats): bank = 7*cell%32, 7 odd -> 2-way
#define GLP     (HIDDEN * GLS)   // gl plane stride in floats (1792)
#define LOG2E   1.44269504088896f

typedef __attribute__((ext_vector_type(8))) _Float16 f16x8;  // MFMA A/B frag
typedef __attribute__((ext_vector_type(4)))  float   f32x4;  // MFMA C/D frag

__device__ __forceinline__ float exp2_f(float x) { return __builtin_amdgcn_exp2f(x); }
__device__ __forceinline__ float rcp_f(float x)  { return __builtin_amdgcn_rcpf(x); }
__device__ __forceinline__ float sigmoid_f(float x) {           // epilogue only
    return rcp_f(1.0f + exp2_f(-LOG2E * x));
}

// R14 post-mortem: (1) VGPR squeeze tracks 512-THREAD blocks (40-48 across
// R3/R6/R13/R14) regardless of launch_bounds -> design INTO <=48: 16 waves
// x 1 gate-tile = ~50 VGPR demand. (2) conflicts unchanged at 22M because
// the READ side was 8-way (stride-20: gcd(5,8) -> period 8); stride-28
// gives bank 7*cell%32 (bijective) -> 2-way reads, 112B rows keep b128
// writes 16B-aligned. R15: 1024 thr, 1 block/CU, 4 waves/SIMD, zero
// duplicated work (48 MFMA/CU/step), 1 cell/lane -> 8 trans/lane (was 32).
// Numerics byte-identical to R12 -> absmax must be exactly 0.00390625.
__global__ __launch_bounds__(NTHREADS, 1)
void lstm_mfma_kernel(const float* __restrict__ x,
                      const float* __restrict__ W_ih,
                      const float* __restrict__ W_hh,
                      const float* __restrict__ b_ih,
                      const float* __restrict__ b_hh,
                      const float* __restrict__ W_fc,
                      const float* __restrict__ b_fc,
                      float* __restrict__ out)
{
    __shared__ __align__(16) _Float16 hA[MB][HIDDEN];      // 2 KB single-buffer
    __shared__ __align__(16) _Float16 xA[2][CS][MB][32];   // 16 KB
    __shared__ __align__(16) float    gl[4][HIDDEN][GLS];  // 28 KB exchange
    __shared__ float hf[MB][HIDDEN];                       // 4 KB epilogue

    const int tid = threadIdx.x;
    const int v   = tid >> 6;        // wave 0..15
    const int l   = tid & 63;
    const int lr  = l & 15;
    const int lg  = l >> 4;
    const int gt  = v >> 2;          // gate type (0=i,1=f,2=g,3=o)
    const int cg  = v & 3;           // cell-group (16 cells)
    const int row0 = blockIdx.x * MB;

    // ---- resident weights: ONE gate-tile per wave (12 VGPR + bias 4) ----
    const float scl = (gt == 2) ? (2.0f * LOG2E) : (-LOG2E);
    const int gate  = gt * 64 + cg * 16 + lr;
    f16x8 Bh[2], Bx;
    f32x4 biasv;
    {
        const float b = scl * (b_ih[gate] + b_hh[gate]);
        biasv = (f32x4){b, b, b, b};
        #pragma unroll
        for (int kf = 0; kf < 2; ++kf)
            #pragma unroll
            for (int j = 0; j < 8; ++j)
                Bh[kf][j] = (_Float16)(scl * W_hh[gate * HIDDEN + kf * 32 + lg * 8 + j]);
        #pragma unroll
        for (int j = 0; j < 8; ++j) {
            const int k = lg * 8 + j;
            Bx[j] = (_Float16)((k < INPUT) ? scl * W_ih[gate * INPUT + k] : 0.0f);
        }
    }

    // ---- precomputed LDS pointers ----
    const f16x8* phr[2];             // h A-frag reads (R12 swizzle scheme)
    #pragma unroll
    for (int kf = 0; kf < 2; ++kf) {
        const int slot = (kf * 4 + lg) ^ (lr & 7);
        phr[kf] = (const f16x8*)((const char*)&hA[lr][0] + slot * 16);
    }
    const int slx = lg ^ (lr & 3);   // x A-frag reads
    const f16x8* px = (const f16x8*)((const char*)&xA[0][0][lr][0] + slx * 16);
    // gl write: this wave's D-tile, cell = cg*16+lr, rows lg*4..+3 (one b128)
    float* pglw = &gl[gt][cg * 16 + lr][lg * 4];
    // gl read: this lane's cell = l, row = v; plane via imm offset (GLP)
    const float* pglr = &gl[0][l][v];
    // h write: row v, swizzled slot for cell l (b16; 2-way banks)
    const int kp = (l & 7) | (((l >> 3) ^ (v & 7)) << 3);
    _Float16* pwh = &hA[v][kp];

    // ---- zero LDS (h0 = 0; x pad slots stay 0 forever) ----
    for (int i = tid; i < MB * HIDDEN; i += NTHREADS)
        ((unsigned short*)hA)[i] = 0;
    for (int i = tid; i < 2 * CS * MB * 32; i += NTHREADS)
        ((unsigned short*)xA)[i] = 0;

    float c = 0.0f, hreg = 0.0f;     // this lane's single (row v, cell l)

    // ---- x chunk loader: 2048 slots / 1024 threads = 2 each ----
    float stg[2];
    auto load_chunk = [&](int ch) {
        #pragma unroll
        for (int s = 0; s < 2; ++s) {
            const int idx = tid + s * NTHREADS;  // 0..2047
            const int i   = idx & 15;
            const int tt  = (idx >> 4) & 7;
            const int r   = idx >> 7;            // 0..15
            float vx = 0.0f;
            if (i < INPUT)
                vx = x[(size_t)(row0 + r) * (T_STEPS * INPUT)
                       + (size_t)(ch * CS + tt) * INPUT + i];
            stg[s] = vx;
        }
    };
    auto store_chunk = [&](int buf) {
        #pragma unroll
        for (int s = 0; s < 2; ++s) {
            const int idx = tid + s * NTHREADS;
            const int i   = idx & 15;
            const int tt  = (idx >> 4) & 7;
            const int r   = idx >> 7;
            const int kpx = (i & 7) | (((i >> 3) ^ (r & 3)) << 3);
            xA[buf][tt][r][kpx] = (_Float16)stg[s];
        }
    };

    load_chunk(0);
    __syncthreads();          // zero-init visible
    store_chunk(0);
    __syncthreads();

    for (int ch = 0; ch < NCHUNK; ++ch) {
        const int cur = ch & 1;
        const f16x8* pxc = px + cur * 512;
        if (ch + 1 < NCHUNK)
            load_chunk(ch + 1);          // global loads in flight over 8 steps

        #pragma unroll
        for (int tt = 0; tt < CS; ++tt) {
            // ---- phase A: frag reads + 3-deep MFMA chain + publish ----
            const f16x8 ax  = pxc[tt * 64];
            const f16x8 ah0 = phr[0][0];
            const f16x8 ah1 = phr[1][0];
            f32x4 a = biasv;
            a = __builtin_amdgcn_mfma_f32_16x16x32_f16(ax,  Bx,    a, 0, 0, 0);
            a = __builtin_amdgcn_mfma_f32_16x16x32_f16(ah0, Bh[0], a, 0, 0, 0);
            a = __builtin_amdgcn_mfma_f32_16x16x32_f16(ah1, Bh[1], a, 0, 0, 0);
            *(f32x4*)pglw = a;           // one aligned b128
            __syncthreads();

            // ---- phase B: 1 cell/lane, combined-rcp algebra ----
            {
                const float A = exp2_f(pglr[0 * GLP]);   // e^{-pre_i}
                const float F = exp2_f(pglr[1 * GLP]);   // e^{-pre_f}
                const float B = exp2_f(pglr[2 * GLP]);   // e^{+2 pre_g}
                const float O = exp2_f(pglr[3 * GLP]);   // e^{-pre_o}
                const float ig = (B - 1.0f) * rcp_f((1.0f + A) * (1.0f + B));
                const float cn = fmaf(c, rcp_f(1.0f + F), ig);
                c = cn;
                const float T = exp2_f((2.0f * LOG2E) * cn);
                const float h = (T - 1.0f) * rcp_f((1.0f + O) * (1.0f + T));
                hreg = h;
                pwh[0] = (_Float16)h;
            }

            // fold chunk staging into the last step (no extra barrier)
            if (tt == CS - 1 && ch + 1 < NCHUNK)
                store_chunk(1 - cur);

            __syncthreads();             // h_t complete; gl reusable
        }
    }

    // ---- epilogue: out[row] = sigmoid(h_T . W_fc + b_fc) ----
    hf[v][l] = hreg;
    __syncthreads();
    if (tid < MB) {
        float a = b_fc[0];
        #pragma unroll
        for (int j = 0; j < HIDDEN; ++j)
            a = fmaf(hf[tid][j], W_fc[j], a);
        out[row0 + tid] = sigmoid_f(a);
    }
}

extern "C" void kernel_launch(void* const* d_in, const int* in_sizes, int n_in,
                              void* d_out, int out_size, void* d_ws, size_t ws_size,
                              hipStream_t stream) {
    const float* x    = (const float*)d_in[0];
    const float* W_ih = (const float*)d_in[1];
    const float* W_hh = (const float*)d_in[2];
    const float* b_ih = (const float*)d_in[3];
    const float* b_hh = (const float*)d_in[4];
    const float* W_fc = (const float*)d_in[5];
    const float* b_fc = (const float*)d_in[6];
    float* out = (float*)d_out;

    const int B = 4096;
    dim3 grid(B / MB), block(NTHREADS);
    lstm_mfma_kernel<<<grid, block, 0, stream>>>(x, W_ih, W_hh, b_ih, b_hh,
                                                 W_fc, b_fc, out);
}

// Round 16
// 300.288 us; speedup vs baseline: 1.1586x; 1.1100x over previous
//
#include <hip/hip_runtime.h>

#define T_STEPS 512
#define INPUT   13
#define HIDDEN  64
#define MB      16    // full MFMA M-tile, grid 256 = 1 block/CU
#define CS      8     // timesteps per x-chunk
#define NCHUNK  (T_STEPS / CS)
#define NTHREADS 512  // 8 waves: gt = w>>1, cell-half = (w&1)*2 (2 tiles each)
#define GLS     68    // gl row stride (floats): 68%32=4 -> banks (4*row+cell)%32
#define GLP     (MB * GLS)       // gl plane stride: 1088 floats
#define LOG2E   1.44269504088896f

typedef __attribute__((ext_vector_type(8))) _Float16 f16x8;  // MFMA A/B frag
typedef __attribute__((ext_vector_type(4)))  float   f32x4;  // MFMA C/D frag

__device__ __forceinline__ float exp2_f(float x) { return __builtin_amdgcn_exp2f(x); }
__device__ __forceinline__ float rcp_f(float x)  { return __builtin_amdgcn_rcpf(x); }
__device__ __forceinline__ float sigmoid_f(float x) {           // epilogue only
    return rcp_f(1.0f + exp2_f(-LOG2E * x));
}

// R15 post-mortem: (a) per-SIMD VALU issue is INVARIANT under wave-split --
// extra waves only hide R12's ~530 cyc of exposed MFMA-issue+latency; (b)
// stride-28 bank step = 28 mod 32 (period 8 -> 8-way), my 3rd bank error;
// (c) 1024-thr blocks squeeze VGPR to 24. R16 fixes by construction:
//  - gl stride 68 floats: writes bank (16(lg&1)+lr+4r)%32 = 32 distinct
//    (2-way free); reads (row uniform/wave) bank (4rho+l)%32 (2-way free);
//    LINEAR addressing -> 1 base ptr + imm each side.
//  - 512 thr (band 40-48), demand ~46: 24 weight VGPR; bias folded into
//    Bx via x[13]==1.0 pad slot (0 VGPR, 0 VALU); single-buffered hA
//    (2-barrier phase structure separates read/write); no hreg/hf.
// Gate: dur >= 225 kills the split concept -> revert to R12.
__global__ __launch_bounds__(NTHREADS, 1)
void lstm_mfma_kernel(const float* __restrict__ x,
                      const float* __restrict__ W_ih,
                      const float* __restrict__ W_hh,
                      const float* __restrict__ b_ih,
                      const float* __restrict__ b_hh,
                      const float* __restrict__ W_fc,
                      const float* __restrict__ b_fc,
                      float* __restrict__ out)
{
    __shared__ __align__(16) _Float16 hA[MB][HIDDEN];      // 2 KB single-buffer
    __shared__ __align__(16) _Float16 xA[2][CS][MB][32];   // 16 KB
    __shared__ __align__(16) float    gl[4][MB][GLS];      // 17.4 KB exchange

    const int tid = threadIdx.x;
    const int w   = tid >> 6;        // wave 0..7
    const int l   = tid & 63;
    const int lr  = l & 15;
    const int lg  = l >> 4;
    const int gt  = w >> 1;          // gate type (0=i,1=f,2=g,3=o)
    const int cgb = (w & 1) * 2;     // first of two owned cell-tiles
    const int row0 = blockIdx.x * MB;

    // ---- resident weights: 2 gate-tiles; bias lives in Bx at k==13 ----
    const float scl = (gt == 2) ? (2.0f * LOG2E) : (-LOG2E);
    f16x8 Bh[2][2], Bx[2];
    #pragma unroll
    for (int t = 0; t < 2; ++t) {
        const int gate = gt * 64 + (cgb + t) * 16 + lr;
        #pragma unroll
        for (int kf = 0; kf < 2; ++kf)
            #pragma unroll
            for (int j = 0; j < 8; ++j)
                Bh[t][kf][j] = (_Float16)(scl * W_hh[gate * HIDDEN + kf * 32 + lg * 8 + j]);
        #pragma unroll
        for (int j = 0; j < 8; ++j) {
            const int k = lg * 8 + j;
            float v = 0.0f;
            if (k < INPUT)       v = scl * W_ih[gate * INPUT + k];
            else if (k == INPUT) v = scl * (b_ih[gate] + b_hh[gate]);  // x[13]=1
            Bx[t][j] = (_Float16)v;
        }
    }

    // ---- precomputed LDS pointers (all linear + imm offsets) ----
    const f16x8* phr[2];             // h A-frag reads (proven swizzle)
    #pragma unroll
    for (int kf = 0; kf < 2; ++kf) {
        const int slot = (kf * 4 + lg) ^ (lr & 7);
        phr[kf] = (const f16x8*)((const char*)&hA[lr][0] + slot * 16);
    }
    const int slx = lg ^ (lr & 3);   // x A-frag reads
    const f16x8* px = (const f16x8*)((const char*)&xA[0][0][lr][0] + slx * 16);
    // gl write: + r*GLS + t*16 (imm). banks: (16(lg&1)+lr+4r)%32 -> 2-way
    float* pgw = &gl[gt][4 * lg][cgb * 16 + lr];
    // gl read: + gt*GLP + d*8*GLS (imm). banks: (4*row+l)%32 -> 2-way
    const float* pglr = &gl[0][w][l];
    // h write: rows w, w+8 share kp ((w+8)&7 == w&7); +d*512 f16 (imm)
    const int kp = (l & 7) | (((l >> 3) ^ (w & 7)) << 3);
    _Float16* pwh = &hA[w][kp];

    // ---- zero LDS (h0 = 0; x pad slots k>=14 stay 0; k==13 set by stager) ----
    for (int i = tid; i < MB * HIDDEN; i += NTHREADS)
        ((unsigned short*)hA)[i] = 0;
    for (int i = tid; i < 2 * CS * MB * 32; i += NTHREADS)
        ((unsigned short*)xA)[i] = 0;

    float c[2] = {0.f, 0.f};         // cells (row w, l) and (row w+8, l)

    // ---- x chunk loader: 2048 slots / 512 threads = 4 each ----
    float stg[4];
    auto load_chunk = [&](int ch) {
        #pragma unroll
        for (int s = 0; s < 4; ++s) {
            const int idx = tid + s * NTHREADS;  // 0..2047
            const int i   = idx & 15;
            const int tt  = (idx >> 4) & 7;
            const int r   = idx >> 7;            // 0..15
            float v = 0.0f;
            if (i < INPUT)
                v = x[(size_t)(row0 + r) * (T_STEPS * INPUT)
                      + (size_t)(ch * CS + tt) * INPUT + i];
            else if (i == INPUT)
                v = 1.0f;                        // bias lane
            stg[s] = v;
        }
    };
    auto store_chunk = [&](int buf) {
        #pragma unroll
        for (int s = 0; s < 4; ++s) {
            const int idx = tid + s * NTHREADS;
            const int i   = idx & 15;
            const int tt  = (idx >> 4) & 7;
            const int r   = idx >> 7;
            const int kpx = (i & 7) | (((i >> 3) ^ (r & 3)) << 3);
            xA[buf][tt][r][kpx] = (_Float16)stg[s];
        }
    };

    load_chunk(0);
    __syncthreads();          // zero-init visible
    store_chunk(0);
    __syncthreads();

    for (int ch = 0; ch < NCHUNK; ++ch) {
        const int cur = ch & 1;
        const f16x8* pxc = px + cur * 512;
        if (ch + 1 < NCHUNK)
            load_chunk(ch + 1);          // global loads in flight over 8 steps

        #pragma unroll
        for (int tt = 0; tt < CS; ++tt) {
            // ---- phase A: frag reads + 2 x 3-deep MFMA chains + publish ----
            const f16x8 ax  = pxc[tt * 64];
            const f16x8 ah0 = phr[0][0];
            const f16x8 ah1 = phr[1][0];
            f32x4 a0 = {0.f, 0.f, 0.f, 0.f};
            f32x4 a1 = {0.f, 0.f, 0.f, 0.f};
            a0 = __builtin_amdgcn_mfma_f32_16x16x32_f16(ax,  Bx[0],    a0, 0, 0, 0);
            a1 = __builtin_amdgcn_mfma_f32_16x16x32_f16(ax,  Bx[1],    a1, 0, 0, 0);
            a0 = __builtin_amdgcn_mfma_f32_16x16x32_f16(ah0, Bh[0][0], a0, 0, 0, 0);
            a1 = __builtin_amdgcn_mfma_f32_16x16x32_f16(ah0, Bh[1][0], a1, 0, 0, 0);
            a0 = __builtin_amdgcn_mfma_f32_16x16x32_f16(ah1, Bh[0][1], a0, 0, 0, 0);
            a1 = __builtin_amdgcn_mfma_f32_16x16x32_f16(ah1, Bh[1][1], a1, 0, 0, 0);
            #pragma unroll
            for (int r = 0; r < 4; ++r) {
                pgw[r * GLS]      = a0[r];
                pgw[r * GLS + 16] = a1[r];
            }
            __syncthreads();

            // ---- phase B: rows w, w+8 x cell l; combined-rcp algebra ----
            #pragma unroll
            for (int d = 0; d < 2; ++d) {
                const int off = d * 8 * GLS;
                const float A = exp2_f(pglr[off + 0 * GLP]);   // e^{-pre_i}
                const float F = exp2_f(pglr[off + 1 * GLP]);   // e^{-pre_f}
                const float B = exp2_f(pglr[off + 2 * GLP]);   // e^{+2 pre_g}
                const float O = exp2_f(pglr[off + 3 * GLP]);   // e^{-pre_o}
                const float ig = (B - 1.0f) * rcp_f((1.0f + A) * (1.0f + B));
                const float cn = fmaf(c[d], rcp_f(1.0f + F), ig);
                c[d] = cn;
                const float T = exp2_f((2.0f * LOG2E) * cn);
                const float h = (T - 1.0f) * rcp_f((1.0f + O) * (1.0f + T));
                pwh[d * 512] = (_Float16)h;    // row w+8 = +512 f16
            }

            // fold chunk staging into the last step (no extra barrier)
            if (tt == CS - 1 && ch + 1 < NCHUNK)
                store_chunk(1 - cur);

            __syncthreads();
        }
    }

    // ---- epilogue: out[row] = sigmoid(h_T . W_fc + b_fc), h from hA ----
    if (tid < MB) {
        float a = b_fc[0];
        #pragma unroll
        for (int j = 0; j < HIDDEN; ++j) {
            const int kpj = (j & 7) | (((j >> 3) ^ (tid & 7)) << 3);
            a = fmaf((float)hA[tid][kpj], W_fc[j], a);
        }
        out[row0 + tid] = sigmoid_f(a);
    }
}

extern "C" void kernel_launch(void* const* d_in, const int* in_sizes, int n_in,
                              void* d_out, int out_size, void* d_ws, size_t ws_size,
                              hipStream_t stream) {
    const float* x    = (const float*)d_in[0];
    const float* W_ih = (const float*)d_in[1];
    const float* W_hh = (const float*)d_in[2];
    const float* b_ih = (const float*)d_in[3];
    const float* b_hh = (const float*)d_in[4];
    const float* W_fc = (const float*)d_in[5];
    const float* b_fc = (const float*)d_in[6];
    float* out = (float*)d_out;

    const int B = 4096;
    dim3 grid(B / MB), block(NTHREADS);
    lstm_mfma_kernel<<<grid, block, 0, stream>>>(x, W_ih, W_hh, b_ih, b_hh,
                                                 W_fc, b_fc, out);
}

// Round 17
// 225.494 us; speedup vs baseline: 1.5428x; 1.3317x over previous
//
#include <hip/hip_runtime.h>

#define T_STEPS 512
#define INPUT   13
#define HIDDEN  64
#define MB      16    // full MFMA M-tile, grid 256 = 1 block/CU
#define CS      8     // timesteps per x-chunk
#define NCHUNK  (T_STEPS / CS)
#define LOG2E   1.44269504088896f

typedef __attribute__((ext_vector_type(8))) _Float16 f16x8;  // MFMA A/B frag
typedef __attribute__((ext_vector_type(4)))  float   f32x4;  // MFMA C/D frag

__device__ __forceinline__ float exp2_f(float x) { return __builtin_amdgcn_exp2f(x); }
__device__ __forceinline__ float rcp_f(float x)  { return __builtin_amdgcn_rcpf(x); }
__device__ __forceinline__ float sigmoid_f(float x) {           // epilogue only
    return rcp_f(1.0f + exp2_f(-LOG2E * x));
}

// R16 post-mortem: 4th and cleanest wave-split attempt (conflicts fixed,
// linear exchange) still lost 300 vs R12's 225 -> the recurrence forbids
// cross-step pipelining and within-step splitting adds an exchange to the
// same serial path. Concept dead per R15 gate; revert to R12.
// R17 = R12 + latency polish: software-pipeline the x-MFMA (axacc for step
// t+1 issued during step t -- independent of h_t), shrinking the post-
// barrier dep chain to ds_read -> 2 MFMA -> trans; the 4 x-MFMAs + x read
// overlap h-read latency and the trans phase (separate pipes). 7/8 steps
// pipelined (chunk-boundary refills inline). Math bit-identical to R12
// (same chain order x,h0,h1) -> absmax must be exactly 0.00390625.
__global__ __launch_bounds__(256, 1)
void lstm_mfma_kernel(const float* __restrict__ x,
                      const float* __restrict__ W_ih,
                      const float* __restrict__ W_hh,
                      const float* __restrict__ b_ih,
                      const float* __restrict__ b_hh,
                      const float* __restrict__ W_fc,
                      const float* __restrict__ b_fc,
                      float* __restrict__ out)
{
    // h frags: [buf][row][k] f16, slot ^= row&7 swizzle (slot = 16B)
    __shared__ _Float16 hA[2][MB][HIDDEN];         // 4 KB
    // x frags: [buf][tt][row][k(32, zero-padded)] f16, slot ^= row&3
    __shared__ _Float16 xA[2][CS][MB][32];         // 16 KB

    const int tid = threadIdx.x;
    const int w   = tid >> 6;      // wave 0..3
    const int l   = tid & 63;
    const int lr  = l & 15;        // MFMA row/col index
    const int lg  = l >> 4;        // MFMA k-group
    const int row0 = blockIdx.x * MB;

    // ---- resident weight B-frags (f16, activation-scale folded) ----
    // sigma gates (i,f,o): scl = -log2e -> exp2(acc) = e^{-pre}
    // g gate:              scl = 2log2e -> exp2(acc) = e^{2 pre}
    f16x8 Bh[4][2], Bx[4];
    f32x4 biasv[4];
    #pragma unroll
    for (int gt = 0; gt < 4; ++gt) {
        const int gate  = gt * 64 + 16 * w + lr;
        const float scl = (gt == 2) ? (2.0f * LOG2E) : (-LOG2E);
        const float b   = scl * (b_ih[gate] + b_hh[gate]);
        biasv[gt] = (f32x4){b, b, b, b};
        #pragma unroll
        for (int kf = 0; kf < 2; ++kf)
            #pragma unroll
            for (int j = 0; j < 8; ++j)
                Bh[gt][kf][j] = (_Float16)(scl * W_hh[gate * HIDDEN + kf * 32 + lg * 8 + j]);
        #pragma unroll
        for (int j = 0; j < 8; ++j) {
            const int k = lg * 8 + j;
            Bx[gt][j] = (_Float16)((k < INPUT) ? scl * W_ih[gate * INPUT + k] : 0.0f);
        }
    }

    // ---- precomputed LDS pointers ----
    const f16x8* phr[2][2];        // h reads: [hb][kf] (f16x8 units)
    #pragma unroll
    for (int hb = 0; hb < 2; ++hb)
        #pragma unroll
        for (int kf = 0; kf < 2; ++kf) {
            const int slot = (kf * 4 + lg) ^ (lr & 7);
            phr[hb][kf] = (const f16x8*)((const char*)&hA[hb][lr][0] + slot * 16);
        }
    const int slx = lg ^ (lr & 3); // x reads: pxc[tt*64], buf stride 512 units
    const f16x8* px = (const f16x8*)((const char*)&xA[0][0][lr][0] + slx * 16);
    _Float16* pw[2][4];            // h writes: [hb][r]
    #pragma unroll
    for (int hb = 0; hb < 2; ++hb)
        #pragma unroll
        for (int r = 0; r < 4; ++r) {
            const int row = lg * 4 + r;
            const int k   = 16 * w + lr;
            const int kp  = (k & 7) | (((k >> 3) ^ (row & 7)) << 3);
            pw[hb][r] = &hA[hb][row][kp];
        }

    // ---- zero LDS (h0 = 0; x pad slots stay 0 forever) ----
    for (int i = tid; i < 2 * MB * HIDDEN; i += 256)
        ((unsigned short*)hA)[i] = 0;
    for (int i = tid; i < 2 * CS * MB * 32; i += 256)
        ((unsigned short*)xA)[i] = 0;

    float c[4] = {0.f, 0.f, 0.f, 0.f};

    // ---- x chunk loader: 16 rows x 8 tt x 16 (padded) = 2048 slots ----
    float stg[8];
    auto load_chunk = [&](int ch) {
        #pragma unroll
        for (int s = 0; s < 8; ++s) {
            const int idx = tid + s * 256;   // 0..2047
            const int i   = idx & 15;
            const int tt  = (idx >> 4) & 7;
            const int r   = idx >> 7;        // 0..15
            float v = 0.0f;
            if (i < INPUT)
                v = x[(size_t)(row0 + r) * (T_STEPS * INPUT)
                      + (size_t)(ch * CS + tt) * INPUT + i];
            stg[s] = v;
        }
    };
    auto store_chunk = [&](int buf) {
        #pragma unroll
        for (int s = 0; s < 8; ++s) {
            const int idx = tid + s * 256;
            const int i   = idx & 15;
            const int tt  = (idx >> 4) & 7;
            const int r   = idx >> 7;
            const int kp  = (i & 7) | (((i >> 3) ^ (r & 3)) << 3);
            xA[buf][tt][r][kp] = (_Float16)stg[s];
        }
    };

    load_chunk(0);
    __syncthreads();          // zero-init visible
    store_chunk(0);
    __syncthreads();

    // ---- software-pipelined x-accumulator: axacc = bias + x_t . Wx ----
    f32x4 axacc[4];
    {
        const f16x8 ax0 = px[0];             // (ch=0, tt=0) frag
        #pragma unroll
        for (int gt = 0; gt < 4; ++gt)
            axacc[gt] = __builtin_amdgcn_mfma_f32_16x16x32_f16(ax0, Bx[gt], biasv[gt], 0, 0, 0);
    }

    for (int ch = 0; ch < NCHUNK; ++ch) {
        const int cur = ch & 1;
        const f16x8* pxc = px + cur * 512;
        if (ch + 1 < NCHUNK)
            load_chunk(ch + 1);          // global loads in flight over 8 steps

        // chunk-boundary refill (prev chunk's tt==7 couldn't prefetch:
        // this buffer was only completed at the last barrier)
        if (ch > 0) {
            const f16x8 ax0 = pxc[0];
            #pragma unroll
            for (int gt = 0; gt < 4; ++gt)
                axacc[gt] = __builtin_amdgcn_mfma_f32_16x16x32_f16(ax0, Bx[gt], biasv[gt], 0, 0, 0);
        }

        #pragma unroll
        for (int tt = 0; tt < CS; ++tt) {
            const int hb  = tt & 1;      // read parity (static after unroll)
            const int hbw = hb ^ 1;      // write parity

            // ---- h frag reads (post-barrier critical path) ----
            const f16x8 ah0 = phr[hb][0][0];
            const f16x8 ah1 = phr[hb][1][0];

            // ---- gate GEMM: 2-deep h chain on top of pipelined axacc ----
            f32x4 acc[4];
            #pragma unroll
            for (int gt = 0; gt < 4; ++gt) {
                f32x4 a = __builtin_amdgcn_mfma_f32_16x16x32_f16(ah0, Bh[gt][0], axacc[gt], 0, 0, 0);
                acc[gt]  = __builtin_amdgcn_mfma_f32_16x16x32_f16(ah1, Bh[gt][1], a, 0, 0, 0);
            }

            // ---- prefetch next step's x-MFMA (independent of h_t; fills
            //      the MFMA pipe while the trans phase runs on VALU) ----
            if (tt + 1 < CS) {
                const f16x8 axn = pxc[(tt + 1) * 64];
                #pragma unroll
                for (int gt = 0; gt < 4; ++gt)
                    axacc[gt] = __builtin_amdgcn_mfma_f32_16x16x32_f16(axn, Bx[gt], biasv[gt], 0, 0, 0);
            }

            // ---- cell update: combined-rcp algebra (8 trans/cell) ----
            #pragma unroll
            for (int r = 0; r < 4; ++r) {
                const float A = exp2_f(acc[0][r]);   // e^{-pre_i}
                const float F = exp2_f(acc[1][r]);   // e^{-pre_f}
                const float B = exp2_f(acc[2][r]);   // e^{+2 pre_g}
                const float O = exp2_f(acc[3][r]);   // e^{-pre_o}
                const float ig = (B - 1.0f) * rcp_f((1.0f + A) * (1.0f + B));
                const float cn = fmaf(c[r], rcp_f(1.0f + F), ig);
                c[r] = cn;
                const float T = exp2_f((2.0f * LOG2E) * cn);   // e^{2c}
                const float h = (T - 1.0f) * rcp_f((1.0f + O) * (1.0f + T));
                pw[hbw][r][0] = (_Float16)h;
            }

            // fold chunk staging into the last step (no extra barrier)
            if (tt == CS - 1 && ch + 1 < NCHUNK)
                store_chunk(1 - cur);

            __syncthreads();
        }
    }

    // ---- epilogue: out[row] = sigmoid(h_T . W_fc + b_fc) ----
    // last write parity: tt=7 -> hbw = 0; h_T lives in hA[0]
    if (tid < MB) {
        float a = b_fc[0];
        #pragma unroll
        for (int j = 0; j < HIDDEN; ++j) {
            const int kpj = (j & 7) | (((j >> 3) ^ (tid & 7)) << 3);
            a = fmaf((float)hA[0][tid][kpj], W_fc[j], a);
        }
        out[row0 + tid] = sigmoid_f(a);
    }
}

extern "C" void kernel_launch(void* const* d_in, const int* in_sizes, int n_in,
                              void* d_out, int out_size, void* d_ws, size_t ws_size,
                              hipStream_t stream) {
    const float* x    = (const float*)d_in[0];
    const float* W_ih = (const float*)d_in[1];
    const float* W_hh = (const float*)d_in[2];
    const float* b_ih = (const float*)d_in[3];
    const float* b_hh = (const float*)d_in[4];
    const float* W_fc = (const float*)d_in[5];
    const float* b_fc = (const float*)d_in[6];
    float* out = (float*)d_out;

    const int B = 4096;
    dim3 grid(B / MB), block(256);
    lstm_mfma_kernel<<<grid, block, 0, stream>>>(x, W_ih, W_hh, b_ih, b_hh,
                                                 W_fc, b_fc, out);
}